// Round 5
// baseline (306.534 us; speedup 1.0000x reference)
//
#include <hip/hip_runtime.h>
#include <hip/hip_bf16.h>

#define BB 64
#define TT 2048
#define DD 256
#define EPSF 1e-7f
#define XS_STRIDE 264   // shorts/row: 528 B = 33*16 B -> 16B-aligned b128 reads, ~2-way banks (free)

typedef __attribute__((ext_vector_type(8))) short v8s;   // 8 x bf16 (4 VGPRs) — MFMA A/B frag
typedef __attribute__((ext_vector_type(4))) float v4f;   // MFMA C/D frag

__device__ __forceinline__ float bf2f(unsigned short u) {
    union { unsigned int i; float f; } c;
    c.i = ((unsigned int)u) << 16;
    return c.f;
}

__device__ __forceinline__ unsigned int pack2_bf16(float a, float b) {
    union { __hip_bfloat162 h; unsigned int u; } c;
    c.h = __float22bfloat162_rn(make_float2(a, b));   // v_cvt_pk_bf16_f32, RNE
    return c.u;
}

// exact identity tanh(x) = 1 - 2/(exp(2x)+1)
__device__ __forceinline__ float tanh_fast(float x) {
    float e = __expf(2.0f * x);
    return 1.0f - 2.0f / (e + 1.0f);
}

// ---------------- kernel 1: W[d][e] (fp32) -> Wt[e][d] (bf16), LDS tile transpose ----------------
__global__ __launch_bounds__(256) void pack_wt(const float* __restrict__ W,
                                               unsigned short* __restrict__ Wt) {
    __shared__ float tile[32][33];
    int bx = blockIdx.x & 7;    // d-tile
    int by = blockIdx.x >> 3;   // e-tile
    int r  = threadIdx.x >> 3;        // 0..31
    int c4 = (threadIdx.x & 7) * 4;   // 0,4,...,28
    float4 v = *(const float4*)(W + (size_t)(bx * 32 + r) * DD + by * 32 + c4);
    tile[r][c4 + 0] = v.x; tile[r][c4 + 1] = v.y;
    tile[r][c4 + 2] = v.z; tile[r][c4 + 3] = v.w;
    __syncthreads();
    float a0 = tile[c4 + 0][r], a1 = tile[c4 + 1][r];
    float a2 = tile[c4 + 2][r], a3 = tile[c4 + 3][r];
    uint2 pp = make_uint2(pack2_bf16(a0, a1), pack2_bf16(a2, a3));
    *(uint2*)(Wt + (size_t)(by * 32 + r) * DD + bx * 32 + c4) = pp;
}

// ---------------- kernel 2: fully fused, wave-independent (no mid-kernel barriers) -------------
// Wave = 16 rows. Block = 4 independent waves = 64 rows. Grid = 2048.
// Per wave: stage rows -> private LDS slice; A-frags from LDS; all 16 nt-tiles of e via MFMA
// (B from L2-hot Wt); in-wave e-reduce; p = exp(e)*mask via shuffles; weighted sum from LDS.
// One barrier at the end merges the 4 wave-partials into block outputs.
__global__ __launch_bounds__(256) void fused_att2(const float* __restrict__ x,
                                                  const unsigned short* __restrict__ Wt,
                                                  const float* __restrict__ bias,
                                                  const float* __restrict__ uw,
                                                  const int* __restrict__ mask,
                                                  float* __restrict__ numpart,
                                                  float* __restrict__ denpart) {
    __shared__ unsigned short xs[4 * 16 * XS_STRIDE];   // 33792 B, wave-private slices
    __shared__ float red[4][DD];                        // 4 KB merge buffer
    __shared__ float denred[4];

    const int tid  = threadIdx.x;
    const int w    = tid >> 6;     // wave 0..3
    const int lane = tid & 63;
    const int quad = lane >> 4;    // 0..3
    const int m    = lane & 15;    // 0..15
    const long R0  = (long)blockIdx.x * 64 + w * 16;    // this wave's first row

    unsigned short* xw = xs + (size_t)w * 16 * XS_STRIDE;

    // ---- stage 16 rows (wave-private; compiler inserts lgkmcnt/vmcnt only, no barrier)
    {
        const float* gp = x + R0 * DD + lane * 4;
#pragma unroll 8
        for (int r = 0; r < 16; ++r) {
            float4 v = *(const float4*)(gp + (size_t)r * DD);
            uint2 pp = make_uint2(pack2_bf16(v.x, v.y), pack2_bf16(v.z, v.w));
            *(uint2*)(xw + (size_t)r * XS_STRIDE + lane * 4) = pp;
        }
    }

    // ---- A fragments: A[m][k = quad*8 + j]
    v8s afrag[8];
    {
        const unsigned short* ap = xw + (size_t)m * XS_STRIDE + quad * 8;
#pragma unroll
        for (int ks = 0; ks < 8; ++ks) afrag[ks] = *(const v8s*)(ap + ks * 32);
    }

    // ---- e over all 16 nt-tiles
    float esum[4] = {0.f, 0.f, 0.f, 0.f};
#pragma unroll 2
    for (int nt = 0; nt < 16; ++nt) {
        const int n = nt * 16 + m;
        const unsigned short* bp = Wt + (size_t)n * DD + quad * 8;
        v8s bfrag[8];
#pragma unroll
        for (int ks = 0; ks < 8; ++ks) bfrag[ks] = *(const v8s*)(bp + ks * 32);
        v4f acc = {0.f, 0.f, 0.f, 0.f};
#pragma unroll
        for (int ks = 0; ks < 8; ++ks)
            acc = __builtin_amdgcn_mfma_f32_16x16x32_bf16(afrag[ks], bfrag[ks], acc, 0, 0, 0);
        const float bb = bias[n];
        const float un = uw[n];
#pragma unroll
        for (int r = 0; r < 4; ++r)
            esum[r] += tanh_fast(acc[r] + bb) * un;
    }

    // ---- in-wave reduce over the 16 n-lanes (each 16-lane group -> e of rows quad*4+r)
#pragma unroll
    for (int o = 1; o < 16; o <<= 1)
#pragma unroll
        for (int r = 0; r < 4; ++r)
            esum[r] += __shfl_xor(esum[r], o, 64);

    // ---- p = exp(e) * mask for this quad's 4 rows
    const int4 mv = *(const int4*)(mask + R0 + quad * 4);
    float pr[4];
    pr[0] = __expf(esum[0]) * (float)mv.x;
    pr[1] = __expf(esum[1]) * (float)mv.y;
    pr[2] = __expf(esum[2]) * (float)mv.z;
    pr[3] = __expf(esum[3]) * (float)mv.w;

    // gather all 16 p_t via shuffles (row q*4+r lives in lanes with quad==q)
    float p_all[16];
#pragma unroll
    for (int q = 0; q < 4; ++q)
#pragma unroll
        for (int r = 0; r < 4; ++r)
            p_all[q * 4 + r] = __shfl(pr[r], q * 16 + m, 64);

    float den = 0.f;
#pragma unroll
    for (int t = 0; t < 16; ++t) den += p_all[t];

    // ---- weighted sum from private LDS: lane covers d = lane*4 .. lane*4+3
    float num[4] = {0.f, 0.f, 0.f, 0.f};
    {
        const unsigned short* xp = xw + lane * 4;
#pragma unroll
        for (int t = 0; t < 16; ++t) {
            uint2 xv = *(const uint2*)(xp + (size_t)t * XS_STRIDE);
            float pt = p_all[t];
            num[0] += pt * bf2f((unsigned short)(xv.x & 0xffffu));
            num[1] += pt * bf2f((unsigned short)(xv.x >> 16));
            num[2] += pt * bf2f((unsigned short)(xv.y & 0xffffu));
            num[3] += pt * bf2f((unsigned short)(xv.y >> 16));
        }
    }

    // ---- merge the 4 wave-partials (single barrier, end of kernel)
    *(float4*)&red[w][lane * 4] = make_float4(num[0], num[1], num[2], num[3]);
    if (lane == 0) denred[w] = den;
    __syncthreads();
    float s = red[0][tid] + red[1][tid] + red[2][tid] + red[3][tid];
    numpart[(size_t)blockIdx.x * DD + tid] = s;
    if (tid == 0) denpart[blockIdx.x] = denred[0] + denred[1] + denred[2] + denred[3] ;
}

// ---------------- kernel 3: out[b][d] = sum_c num[b*32+c][d] / (sum_c den[b*32+c] + EPS) ------
__global__ __launch_bounds__(256) void finalize(const float* __restrict__ numpart,
                                                const float* __restrict__ denpart,
                                                float* __restrict__ out) {
    __shared__ float dsh;
    int b = blockIdx.x, d = threadIdx.x;
    if (d == 0) {
        float s = 0.f;
        for (int c = 0; c < 32; ++c) s += denpart[b * 32 + c];
        dsh = s + EPSF;
    }
    __syncthreads();
    float s = 0.f;
#pragma unroll
    for (int c = 0; c < 32; ++c) s += numpart[(size_t)(b * 32 + c) * DD + d];
    out[(size_t)b * DD + d] = s / dsh;
}

extern "C" void kernel_launch(void* const* d_in, const int* in_sizes, int n_in,
                              void* d_out, int out_size, void* d_ws, size_t ws_size,
                              hipStream_t stream) {
    const float* x    = (const float*)d_in[0];  // [64,2048,256] fp32 (bf16-rounded values)
    const float* W    = (const float*)d_in[1];  // [256,256] fp32
    const float* bias = (const float*)d_in[2];  // [256] fp32
    const float* uw   = (const float*)d_in[3];  // [256] fp32
    const int*   mask = (const int*)d_in[4];    // [64,2048] int32
    float*       out  = (float*)d_out;          // [64,256] fp32

    char* ws = (char*)d_ws;
    unsigned short* Wt = (unsigned short*)ws;             // 128 KB bf16 W^T
    float* numpart     = (float*)(ws + 131072);           // 2048*256*4 = 2 MB
    float* denpart     = (float*)(ws + 131072 + 2097152); // 8 KB
    // total ws use: ~2.23 MB

    pack_wt<<<dim3(64), dim3(256), 0, stream>>>(W, Wt);
    fused_att2<<<dim3(2048), dim3(256), 0, stream>>>(x, Wt, bias, uw, mask, numpart, denpart);
    finalize<<<dim3(64), dim3(256), 0, stream>>>(numpart, denpart, out);
}

// Round 6
// 231.622 us; speedup vs baseline: 1.3234x; 1.3234x over previous
//
#include <hip/hip_runtime.h>
#include <hip/hip_bf16.h>

#define BB 64
#define TT 2048
#define DD 256
#define EPSF 1e-7f
#define XS_STRIDE 264   // shorts/row: 528 B = 33*16 B -> 16B-aligned b128 reads, ~2-way banks

typedef __attribute__((ext_vector_type(8))) short v8s;   // 8 x bf16 (4 VGPRs) — MFMA A/B frag
typedef __attribute__((ext_vector_type(4))) float v4f;   // MFMA C/D frag

__device__ __forceinline__ float bf2f(unsigned short u) {
    union { unsigned int i; float f; } c;
    c.i = ((unsigned int)u) << 16;
    return c.f;
}

__device__ __forceinline__ unsigned int pack2_bf16(float a, float b) {
    union { __hip_bfloat162 h; unsigned int u; } c;
    c.h = __float22bfloat162_rn(make_float2(a, b));   // v_cvt_pk_bf16_f32, RNE
    return c.u;
}

// exact identity tanh(x) = 1 - 2/(exp(2x)+1)
__device__ __forceinline__ float tanh_fast(float x) {
    float e = __expf(2.0f * x);
    return 1.0f - 2.0f / (e + 1.0f);
}

// ---------------- kernel 1: W[d][e] (fp32) -> Wt[e][d] (bf16), LDS tile transpose ----------------
__global__ __launch_bounds__(256) void pack_wt(const float* __restrict__ W,
                                               unsigned short* __restrict__ Wt) {
    __shared__ float tile[32][33];
    int bx = blockIdx.x & 7;    // d-tile
    int by = blockIdx.x >> 3;   // e-tile
    int r  = threadIdx.x >> 3;        // 0..31
    int c4 = (threadIdx.x & 7) * 4;   // 0,4,...,28
    float4 v = *(const float4*)(W + (size_t)(bx * 32 + r) * DD + by * 32 + c4);
    tile[r][c4 + 0] = v.x; tile[r][c4 + 1] = v.y;
    tile[r][c4 + 2] = v.z; tile[r][c4 + 3] = v.w;
    __syncthreads();
    float a0 = tile[c4 + 0][r], a1 = tile[c4 + 1][r];
    float a2 = tile[c4 + 2][r], a3 = tile[c4 + 3][r];
    uint2 pp = make_uint2(pack2_bf16(a0, a1), pack2_bf16(a2, a3));
    *(uint2*)(Wt + (size_t)(by * 32 + r) * DD + bx * 32 + c4) = pp;
}

// ---------------- kernel 2: fused, R4 nt-split + reg A-cache + B double-buffer ---------------
// Block = 64 rows, 4 waves. Wave computes partial e over its 4 nt for ALL 64 rows,
// processing m-tiles in pairs with A cached in registers and B prefetched (dbuf).
__global__ __launch_bounds__(256, 3) void fused_att3(const float* __restrict__ x,
                                                     const unsigned short* __restrict__ Wt,
                                                     const float* __restrict__ bias,
                                                     const float* __restrict__ uw,
                                                     const int* __restrict__ mask,
                                                     float* __restrict__ numpart,
                                                     float* __restrict__ denpart) {
    __shared__ unsigned short xs[64 * XS_STRIDE];   // 33792 B, 64 block-rows
    __shared__ float ered[4][64];                   // per-wave e partials
    __shared__ float red[4][DD];                    // num merge
    __shared__ float denred[4];

    const int tid  = threadIdx.x;
    const int w    = tid >> 6;     // wave 0..3
    const int lane = tid & 63;
    const int quad = lane >> 4;    // 0..3
    const int m    = lane & 15;    // 0..15
    const long R0  = (long)blockIdx.x * 64 + w * 16;   // this wave's staging rows

    // hoisted bias/uw for this wave's nt range (n = (w*4+i)*16 + m)
    float bias_r[4], uw_r[4];
#pragma unroll
    for (int i = 0; i < 4; ++i) {
        int n = (w * 4 + i) * 16 + m;
        bias_r[i] = bias[n];
        uw_r[i]   = uw[n];
    }

    // ---- stage this wave's 16 rows into its LDS slice (1 KB coalesced per load)
    {
        const float* gp = x + R0 * DD + lane * 4;
        unsigned short* sp = xs + (size_t)(w * 16) * XS_STRIDE + lane * 4;
#pragma unroll 8
        for (int r = 0; r < 16; ++r) {
            float4 v = *(const float4*)(gp + (size_t)r * DD);
            uint2 pp = make_uint2(pack2_bf16(v.x, v.y), pack2_bf16(v.z, v.w));
            *(uint2*)(sp + (size_t)r * XS_STRIDE) = pp;
        }
    }
    __syncthreads();

    // ---- e-GEMM: halves of m-tiles (pair cached in regs), B double-buffered over nt
    float esum[4][4];   // [mt][r]
#pragma unroll
    for (int mt = 0; mt < 4; ++mt)
#pragma unroll
        for (int r = 0; r < 4; ++r) esum[mt][r] = 0.f;

#pragma unroll
    for (int h = 0; h < 2; ++h) {
        // A fragments for block-rows (2h)*16+m and (2h+1)*16+m
        v8s a0[8], a1[8];
        {
            const unsigned short* ap0 = xs + (size_t)(2 * h * 16 + m) * XS_STRIDE + quad * 8;
#pragma unroll
            for (int ks = 0; ks < 8; ++ks) {
                a0[ks] = *(const v8s*)(ap0 + ks * 32);
                a1[ks] = *(const v8s*)(ap0 + 16 * XS_STRIDE + ks * 32);
            }
        }
        v8s bbuf[2][8];
        {
            const unsigned short* bp = Wt + (size_t)(w * 4 * 16 + m) * DD + quad * 8;
#pragma unroll
            for (int ks = 0; ks < 8; ++ks) bbuf[0][ks] = *(const v8s*)(bp + ks * 32);
        }
#pragma unroll
        for (int i = 0; i < 4; ++i) {
            const int cur = i & 1;
            if (i < 3) {   // prefetch next nt's B while computing on current
                const unsigned short* bp = Wt + (size_t)((w * 4 + i + 1) * 16 + m) * DD + quad * 8;
#pragma unroll
                for (int ks = 0; ks < 8; ++ks) bbuf[cur ^ 1][ks] = *(const v8s*)(bp + ks * 32);
            }
            v4f acc0 = {0.f, 0.f, 0.f, 0.f};
            v4f acc1 = {0.f, 0.f, 0.f, 0.f};
#pragma unroll
            for (int ks = 0; ks < 8; ++ks) {
                acc0 = __builtin_amdgcn_mfma_f32_16x16x32_bf16(a0[ks], bbuf[cur][ks], acc0, 0, 0, 0);
                acc1 = __builtin_amdgcn_mfma_f32_16x16x32_bf16(a1[ks], bbuf[cur][ks], acc1, 0, 0, 0);
            }
#pragma unroll
            for (int r = 0; r < 4; ++r) {
                esum[2 * h][r]     += tanh_fast(acc0[r] + bias_r[i]) * uw_r[i];
                esum[2 * h + 1][r] += tanh_fast(acc1[r] + bias_r[i]) * uw_r[i];
            }
        }
    }

    // ---- reduce over 16 n-lanes; m==0 lanes write this wave's e-partials for all 64 rows
#pragma unroll
    for (int o = 1; o < 16; o <<= 1)
#pragma unroll
        for (int mt = 0; mt < 4; ++mt)
#pragma unroll
            for (int r = 0; r < 4; ++r)
                esum[mt][r] += __shfl_xor(esum[mt][r], o, 64);
    if (m == 0) {
#pragma unroll
        for (int mt = 0; mt < 4; ++mt)
#pragma unroll
            for (int r = 0; r < 4; ++r)
                ered[w][mt * 16 + quad * 4 + r] = esum[mt][r];
    }
    __syncthreads();

    // ---- p for this wave's own 16 rows; broadcast via shuffles
    const int rl = lane & 15;
    float et = ered[0][w * 16 + rl] + ered[1][w * 16 + rl]
             + ered[2][w * 16 + rl] + ered[3][w * 16 + rl];
    float p_loc = __expf(et) * (float)mask[R0 + rl];
    float p_all[16];
#pragma unroll
    for (int t = 0; t < 16; ++t) p_all[t] = __shfl(p_loc, t, 64);
    float den = 0.f;
#pragma unroll
    for (int t = 0; t < 16; ++t) den += p_all[t];

    // ---- weighted sum over own 16 rows from own LDS slice; lane covers d = lane*4..+3
    float num[4] = {0.f, 0.f, 0.f, 0.f};
    {
        const unsigned short* xp = xs + (size_t)(w * 16) * XS_STRIDE + lane * 4;
#pragma unroll
        for (int t = 0; t < 16; ++t) {
            uint2 xv = *(const uint2*)(xp + (size_t)t * XS_STRIDE);
            float pt = p_all[t];
            num[0] += pt * bf2f((unsigned short)(xv.x & 0xffffu));
            num[1] += pt * bf2f((unsigned short)(xv.x >> 16));
            num[2] += pt * bf2f((unsigned short)(xv.y & 0xffffu));
            num[3] += pt * bf2f((unsigned short)(xv.y >> 16));
        }
    }

    // ---- merge 4 wave-partials, single store per block
    *(float4*)&red[w][lane * 4] = make_float4(num[0], num[1], num[2], num[3]);
    if (lane == 0) denred[w] = den;
    __syncthreads();
    float s = red[0][tid] + red[1][tid] + red[2][tid] + red[3][tid];
    numpart[(size_t)blockIdx.x * DD + tid] = s;
    if (tid == 0) denpart[blockIdx.x] = denred[0] + denred[1] + denred[2] + denred[3];
}

// ---------------- kernel 3: out[b][d] = sum_c num[b*32+c][d] / (sum_c den[b*32+c] + EPS) ------
__global__ __launch_bounds__(256) void finalize(const float* __restrict__ numpart,
                                                const float* __restrict__ denpart,
                                                float* __restrict__ out) {
    __shared__ float dsh;
    int b = blockIdx.x, d = threadIdx.x;
    if (d == 0) {
        float s = 0.f;
        for (int c = 0; c < 32; ++c) s += denpart[b * 32 + c];
        dsh = s + EPSF;
    }
    __syncthreads();
    float s = 0.f;
#pragma unroll
    for (int c = 0; c < 32; ++c) s += numpart[(size_t)(b * 32 + c) * DD + d];
    out[(size_t)b * DD + d] = s / dsh;
}

extern "C" void kernel_launch(void* const* d_in, const int* in_sizes, int n_in,
                              void* d_out, int out_size, void* d_ws, size_t ws_size,
                              hipStream_t stream) {
    const float* x    = (const float*)d_in[0];  // [64,2048,256] fp32 (bf16-rounded values)
    const float* W    = (const float*)d_in[1];  // [256,256] fp32
    const float* bias = (const float*)d_in[2];  // [256] fp32
    const float* uw   = (const float*)d_in[3];  // [256] fp32
    const int*   mask = (const int*)d_in[4];    // [64,2048] int32
    float*       out  = (float*)d_out;          // [64,256] fp32

    char* ws = (char*)d_ws;
    unsigned short* Wt = (unsigned short*)ws;             // 128 KB bf16 W^T
    float* numpart     = (float*)(ws + 131072);           // 2 MB
    float* denpart     = (float*)(ws + 131072 + 2097152); // 8 KB

    pack_wt<<<dim3(64), dim3(256), 0, stream>>>(W, Wt);
    fused_att3<<<dim3(2048), dim3(256), 0, stream>>>(x, Wt, bias, uw, mask, numpart, denpart);
    finalize<<<dim3(64), dim3(256), 0, stream>>>(numpart, denpart, out);
}